// Round 7
// baseline (182.327 us; speedup 1.0000x reference)
//
#include <hip/hip_runtime.h>

#define BB 16
#define NN 1024
#define CC 64

typedef __attribute__((ext_vector_type(8))) short short8;
typedef __attribute__((ext_vector_type(4))) float f32x4;

typedef __attribute__((address_space(3))) void lds_void_t;
typedef const __attribute__((address_space(1))) void gbl_void_t;

__device__ __forceinline__ void load_lds16(const void* g, void* l) {
    __builtin_amdgcn_global_load_lds((gbl_void_t*)g, (lds_void_t*)l, 16, 0, 0);
}

__device__ __forceinline__ unsigned short bf16_rne(float f) {
    unsigned u = __float_as_uint(f);
    u += 0x7fffu + ((u >> 16) & 1u);
    return (unsigned short)(u >> 16);
}

// ---------------- Kernel 1: xw = x@W_rel -> bf16 swizzled (B-frag order);
//                  out = x@W_root + b_rel (fp32) ---------------- (unchanged)
extern "C" __global__ __launch_bounds__(256)
void precompute(const float* __restrict__ x, const float* __restrict__ W_rel,
                const float* __restrict__ W_root, const float* __restrict__ b_rel,
                unsigned short* __restrict__ xw_sw, float* __restrict__ out)
{
    __shared__ float wrel_s[64 * 64];
    __shared__ float wroot_s[64 * 64];
    __shared__ float x_s[16 * 68];

    const int t = threadIdx.x;
    #pragma unroll
    for (int k = 0; k < 4; ++k) {
        int i4 = t + 256 * k;
        ((float4*)wrel_s)[i4]  = ((const float4*)W_rel)[i4];
        ((float4*)wroot_s)[i4] = ((const float4*)W_root)[i4];
    }
    const int row0 = blockIdx.x * 16;
    {
        int r = t >> 4, c4 = t & 15;
        *(float4*)(x_s + r * 68 + c4 * 4) = ((const float4*)(x + (size_t)(row0 + r) * CC))[c4];
    }
    __syncthreads();

    const int c4 = t & 15;
    const int r  = t >> 4;
    float aw0 = 0.f, aw1 = 0.f, aw2 = 0.f, aw3 = 0.f;
    float ar0 = 0.f, ar1 = 0.f, ar2 = 0.f, ar3 = 0.f;
    const float* xrow = x_s + r * 68;
    #pragma unroll 8
    for (int k = 0; k < 64; ++k) {
        float xv = xrow[k];
        float4 wv = ((const float4*)(wrel_s  + k * 64))[c4];
        float4 rv = ((const float4*)(wroot_s + k * 64))[c4];
        aw0 += xv * wv.x; aw1 += xv * wv.y; aw2 += xv * wv.z; aw3 += xv * wv.w;
        ar0 += xv * rv.x; ar1 += xv * rv.y; ar2 += xv * rv.z; ar3 += xv * rv.w;
    }

    const int row_g = row0 + r;
    {
        const float4 bv = ((const float4*)b_rel)[c4];
        ((float4*)out)[(size_t)row_g * 16 + c4] =
            make_float4(ar0 + bv.x, ar1 + bv.y, ar2 + bv.z, ar3 + bv.w);
    }
    {
        const int b = row_g >> 10;
        const int k = row_g & 1023;
        const int kb = k >> 5;
        const int qk = (k >> 3) & 3;
        const int j  = k & 7;
        const int c  = 4 * c4;
        const int n0 = c >> 4;
        const int n  = c & 15;
        size_t off = ((size_t)b << 16) + (size_t)((kb * 4 + n0) << 9)
                   + (size_t)((n + (qk << 4)) << 3) + j;
        xw_sw[off]      = bf16_rne(aw0);
        xw_sw[off + 8]  = bf16_rne(aw1);
        xw_sw[off + 16] = bf16_rne(aw2);
        xw_sw[off + 24] = bf16_rne(aw3);
    }
}

// ---------------- Kernel 2: out += (adj .* w_edge[ea]) @ xw  (bf16 MFMA) ----
// grid = B * (N/64) = 256 blocks x 1024 threads (16 waves = 4 wm x 4 wk).
// Block = (batch, 64-row m-tile, FULL K=1024). xw staged to LDS once per block
// in two 64 KB phase-buffers (32 MB total traffic, 2x less than R6); adj/ea
// streamed straight to registers (the ~4.9 TB/s path measured in R2-R4).
// Total vmem traffic ~160 MB vs R6's 192 MB. Full-K blocks -> plain RMW, no
// atomics. Epilogue scratch aliases phase-0 buffer.
extern "C" __global__ __launch_bounds__(1024, 4)
void gnn_mfma(const float* __restrict__ adj, const int* __restrict__ ea,
              const float* __restrict__ w_edge,
              const unsigned short* __restrict__ xw_sw,
              float* __restrict__ out)
{
    __shared__ __align__(16) char lds[131072];   // 2 x 64 KB xw phase buffers

    const int t    = threadIdx.x;
    const int w    = t >> 6;              // 0..15
    const int lane = t & 63;
    const int m    = lane & 15;
    const int q    = lane >> 4;
    const int wm   = w >> 2;              // 0..3: 16-row m-frag
    const int wk   = w & 3;               // 0..3: K quarter of each phase

    const int mt = blockIdx.x & 3;        // 4 m-tiles of 64 rows... (see below)
    // grid = 16 b * 16 mtiles: decode properly
    const int mtile = blockIdx.x & 15;
    const int b     = blockIdx.x >> 4;
    const int row0  = mtile << 6;
    (void)mt;

    // cubic through (e, w_edge[e]) for e=0..3 — exact branchless gather
    const float w0 = w_edge[0], w1 = w_edge[1], w2 = w_edge[2], w3 = w_edge[3];
    const float d1 = w1 - w0;
    const float d2 = w2 - 2.f * w1 + w0;
    const float d3 = w3 - 3.f * w2 + 3.f * w1 - w0;
    const float c3 = d3 * (1.f / 6.f);
    const float c2 = 0.5f * d2 - 0.5f * d3;
    const float c1 = d1 - 0.5f * d2 + (1.f / 3.f) * d3;
    const float c0 = w0;

    const int row = row0 + (wm << 4) + m;
    const float* arow = adj + (((size_t)b << 10) + row) * NN;
    const int*   erow = ea  + (((size_t)b << 10) + row) * NN;
    const char*  xwb  = (const char*)xw_sw + ((size_t)b << 17);   // 128 KB/batch

    // ---- stage xw phase p (64 KB contiguous, already B-frag order) ----
    #define STAGE_XW(p)                                                   \
    {                                                                     \
        _Pragma("unroll")                                                 \
        for (int r = 0; r < 4; ++r) {                                     \
            int off = ((p) << 16) + ((w * 4 + r) << 10) + (lane << 4);    \
            load_lds16(xwb + off, lds + off);                             \
        }                                                                 \
    }

    STAGE_XW(0);
    __syncthreads();          // drain phase-0 DMA
    STAGE_XW(1);              // phase-1 DMA rides under phase-0 compute

    f32x4 acc0 = {0.f, 0.f, 0.f, 0.f};
    f32x4 acc1 = acc0, acc2 = acc0, acc3 = acc0;

    #pragma unroll
    for (int p = 0; p < 2; ++p) {
        if (p) __syncthreads();           // phase-1 DMA drained (+ buffer0 reads done)
        #pragma unroll
        for (int kk = 0; kk < 4; ++kk) {
            const int kbl = (wk << 2) + kk;               // 0..15 within phase
            const int gk  = (p << 9) + (kbl << 5) + (q << 3);
            float4 a0 = *(const float4*)(arow + gk);
            float4 a1 = *(const float4*)(arow + gk + 4);
            int4   e0 = *(const int4*)  (erow + gk);
            int4   e1 = *(const int4*)  (erow + gk + 4);

            const char* xbase = lds + (p << 16) + ((kbl << 2) << 10) + (lane << 4);
            short8 bf0 = *(const short8*)(xbase);
            short8 bf1 = *(const short8*)(xbase + 1024);
            short8 bf2 = *(const short8*)(xbase + 2048);
            short8 bf3 = *(const short8*)(xbase + 3072);

            #define WSEL(ev) __builtin_fmaf(__builtin_fmaf(__builtin_fmaf(c3, (float)(ev), c2), (float)(ev), c1), (float)(ev), c0)
            float p0 = a0.x * WSEL(e0.x);
            float p1 = a0.y * WSEL(e0.y);
            float p2 = a0.z * WSEL(e0.z);
            float p3 = a0.w * WSEL(e0.w);
            float p4 = a1.x * WSEL(e1.x);
            float p5 = a1.y * WSEL(e1.y);
            float p6 = a1.z * WSEL(e1.z);
            float p7 = a1.w * WSEL(e1.w);
            #undef WSEL

            union { int i[4]; short8 s8; } af;
            af.i[0] = __builtin_amdgcn_perm(__float_as_uint(p1), __float_as_uint(p0), 0x07060302u);
            af.i[1] = __builtin_amdgcn_perm(__float_as_uint(p3), __float_as_uint(p2), 0x07060302u);
            af.i[2] = __builtin_amdgcn_perm(__float_as_uint(p5), __float_as_uint(p4), 0x07060302u);
            af.i[3] = __builtin_amdgcn_perm(__float_as_uint(p7), __float_as_uint(p6), 0x07060302u);

            acc0 = __builtin_amdgcn_mfma_f32_16x16x32_bf16(af.s8, bf0, acc0, 0, 0, 0);
            acc1 = __builtin_amdgcn_mfma_f32_16x16x32_bf16(af.s8, bf1, acc1, 0, 0, 0);
            acc2 = __builtin_amdgcn_mfma_f32_16x16x32_bf16(af.s8, bf2, acc2, 0, 0, 0);
            acc3 = __builtin_amdgcn_mfma_f32_16x16x32_bf16(af.s8, bf3, acc3, 0, 0, 0);
        }
    }
    #undef STAGE_XW

    // ---- 4-way wk combine via LDS (stride 68, conflict-free), plain RMW out ----
    __syncthreads();                       // buffer reads done -> scratch may alias
    float* scratch = (float*)lds;          // 3 wk-sets x 4 wm x 1088 floats = 52 KB
    if (wk != 0) {
        float* buf = scratch + ((wk - 1) * 4 + wm) * 1088;
        #pragma unroll
        for (int rg = 0; rg < 4; ++rg) {
            int rbase = (q * 4 + rg) * 68 + m;
            buf[rbase]      = acc0[rg];
            buf[rbase + 16] = acc1[rg];
            buf[rbase + 32] = acc2[rg];
            buf[rbase + 48] = acc3[rg];
        }
    }
    __syncthreads();
    if (wk == 0) {
        const float* s1 = scratch + (0 * 4 + wm) * 1088;
        const float* s2 = scratch + (1 * 4 + wm) * 1088;
        const float* s3 = scratch + (2 * 4 + wm) * 1088;
        float* obase = out + (((size_t)b << 10) + row0 + (wm << 4)) * 64;
        #pragma unroll
        for (int rg = 0; rg < 4; ++rg) {
            int rpad = (q * 4 + rg) * 68 + m;
            int rout = (q * 4 + rg) * 64 + m;
            #pragma unroll
            for (int n0 = 0; n0 < 4; ++n0) {
                float v = (n0 == 0 ? acc0[rg] : n0 == 1 ? acc1[rg] : n0 == 2 ? acc2[rg] : acc3[rg]);
                v += s1[rpad + n0 * 16] + s2[rpad + n0 * 16] + s3[rpad + n0 * 16];
                obase[rout + n0 * 16] += v;     // block owns these elements: no atomics
            }
        }
    }
}

extern "C" void kernel_launch(void* const* d_in, const int* in_sizes, int n_in,
                              void* d_out, int out_size, void* d_ws, size_t ws_size,
                              hipStream_t stream) {
    const float* x      = (const float*)d_in[0];
    const float* adj    = (const float*)d_in[1];
    const int*   ea     = (const int*)  d_in[2];
    const float* W_rel  = (const float*)d_in[3];
    const float* b_rel  = (const float*)d_in[4];
    const float* W_root = (const float*)d_in[5];
    const float* w_edge = (const float*)d_in[6];
    float* out = (float*)d_out;

    unsigned short* xw_sw = (unsigned short*)d_ws;   // B*N*C bf16 = 2 MiB

    precompute<<<BB * NN / 16, 256, 0, stream>>>(x, W_rel, W_root, b_rel, xw_sw, out);
    gnn_mfma<<<BB * (NN / 64), 1024, 0, stream>>>(adj, ea, w_edge, xw_sw, out);
}

// Round 8
// 171.617 us; speedup vs baseline: 1.0624x; 1.0624x over previous
//
#include <hip/hip_runtime.h>

#define BB 16
#define NN 1024
#define CC 64

typedef __attribute__((ext_vector_type(8))) short short8;
typedef __attribute__((ext_vector_type(4))) float f32x4;

typedef __attribute__((address_space(3))) void lds_void_t;
typedef const __attribute__((address_space(1))) void gbl_void_t;

__device__ __forceinline__ void load_lds16(const void* g, void* l) {
    __builtin_amdgcn_global_load_lds((gbl_void_t*)g, (lds_void_t*)l, 16, 0, 0);
}

__device__ __forceinline__ unsigned short bf16_rne(float f) {
    unsigned u = __float_as_uint(f);
    u += 0x7fffu + ((u >> 16) & 1u);
    return (unsigned short)(u >> 16);
}

// ---------------- Kernel 1: xw = x@W_rel -> bf16 swizzled (B-frag order);
//                  out = x@W_root + b_rel (fp32) ---------------- (unchanged)
extern "C" __global__ __launch_bounds__(256)
void precompute(const float* __restrict__ x, const float* __restrict__ W_rel,
                const float* __restrict__ W_root, const float* __restrict__ b_rel,
                unsigned short* __restrict__ xw_sw, float* __restrict__ out)
{
    __shared__ float wrel_s[64 * 64];
    __shared__ float wroot_s[64 * 64];
    __shared__ float x_s[16 * 68];

    const int t = threadIdx.x;
    #pragma unroll
    for (int k = 0; k < 4; ++k) {
        int i4 = t + 256 * k;
        ((float4*)wrel_s)[i4]  = ((const float4*)W_rel)[i4];
        ((float4*)wroot_s)[i4] = ((const float4*)W_root)[i4];
    }
    const int row0 = blockIdx.x * 16;
    {
        int r = t >> 4, c4 = t & 15;
        *(float4*)(x_s + r * 68 + c4 * 4) = ((const float4*)(x + (size_t)(row0 + r) * CC))[c4];
    }
    __syncthreads();

    const int c4 = t & 15;
    const int r  = t >> 4;
    float aw0 = 0.f, aw1 = 0.f, aw2 = 0.f, aw3 = 0.f;
    float ar0 = 0.f, ar1 = 0.f, ar2 = 0.f, ar3 = 0.f;
    const float* xrow = x_s + r * 68;
    #pragma unroll 8
    for (int k = 0; k < 64; ++k) {
        float xv = xrow[k];
        float4 wv = ((const float4*)(wrel_s  + k * 64))[c4];
        float4 rv = ((const float4*)(wroot_s + k * 64))[c4];
        aw0 += xv * wv.x; aw1 += xv * wv.y; aw2 += xv * wv.z; aw3 += xv * wv.w;
        ar0 += xv * rv.x; ar1 += xv * rv.y; ar2 += xv * rv.z; ar3 += xv * rv.w;
    }

    const int row_g = row0 + r;
    {
        const float4 bv = ((const float4*)b_rel)[c4];
        ((float4*)out)[(size_t)row_g * 16 + c4] =
            make_float4(ar0 + bv.x, ar1 + bv.y, ar2 + bv.z, ar3 + bv.w);
    }
    {
        const int b = row_g >> 10;
        const int k = row_g & 1023;
        const int kb = k >> 5;
        const int qk = (k >> 3) & 3;
        const int j  = k & 7;
        const int c  = 4 * c4;
        const int n0 = c >> 4;
        const int n  = c & 15;
        size_t off = ((size_t)b << 16) + (size_t)((kb * 4 + n0) << 9)
                   + (size_t)((n + (qk << 4)) << 3) + j;
        xw_sw[off]      = bf16_rne(aw0);
        xw_sw[off + 8]  = bf16_rne(aw1);
        xw_sw[off + 16] = bf16_rne(aw2);
        xw_sw[off + 24] = bf16_rne(aw3);
    }
}

// ---------------- Kernel 2: out += (adj .* w_edge[ea]) @ xw  (bf16 MFMA) ----
// grid = B * (N/32) = 512 blocks x 256 threads (4 waves), FULL K per block.
// KEY CHANGE vs R2-R7: every global load instruction covers 1 KB CONTIGUOUS
// memory (64 lanes x 16 B of ONE adj/ea row-segment), matching the 6.3 TB/s
// copy pattern — instead of 16 rows x 128 B scattered across DRAM pages
// (which pinned HBM at ~1.6 TB/s in all prior rounds). The weighted A-tile is
// packed to bf16 in-flight and ds_written to LDS (row-major, +16 B pad);
// A-fragments then come from ds_read_b128. xw staged by contiguous DMA.
// LDS 48.5 KB -> 3 blocks/CU. Wave = (m-frag, k-half-of-chunk); 2-way reduce.
#define AW_STR  528              // 256 bf16 cols * 2 B + 16 B pad
#define XW_OFF_L 16896           // aw region = 32 * 528 B

extern "C" __global__ __launch_bounds__(256, 3)
void gnn_mfma(const float* __restrict__ adj, const int* __restrict__ ea,
              const float* __restrict__ w_edge,
              const unsigned short* __restrict__ xw_sw,
              float* __restrict__ out)
{
    __shared__ __align__(16) char lds[49664];   // aw 16.5 KB | xw 32 KB

    const int t    = threadIdx.x;
    const int w    = t >> 6;
    const int lane = t & 63;
    const int m    = lane & 15;
    const int q    = lane >> 4;
    const int mf   = w & 1;               // m-frag (16 rows) owned for output
    const int kh   = w >> 1;              // k-half of each chunk

    const int mtile = blockIdx.x & 31;
    const int b     = blockIdx.x >> 5;
    const int row0  = mtile << 5;

    // cubic through (e, w_edge[e]) for e=0..3 — exact branchless gather
    const float w0 = w_edge[0], w1 = w_edge[1], w2 = w_edge[2], w3 = w_edge[3];
    const float d1 = w1 - w0;
    const float d2 = w2 - 2.f * w1 + w0;
    const float d3 = w3 - 3.f * w2 + 3.f * w1 - w0;
    const float c3 = d3 * (1.f / 6.f);
    const float c2 = 0.5f * d2 - 0.5f * d3;
    const float c1 = d1 - 0.5f * d2 + (1.f / 3.f) * d3;
    const float c0 = w0;

    const size_t growbase = ((size_t)b << 10) + row0;           // global row index base
    const char*  xwb = (const char*)xw_sw + ((size_t)b << 17);  // 128 KB per batch

    f32x4 acc0 = {0.f, 0.f, 0.f, 0.f};
    f32x4 acc1 = acc0, acc2 = acc0, acc3 = acc0;

    #pragma unroll 1
    for (int c = 0; c < 4; ++c) {                // K chunks of 256
        if (c) __syncthreads();                  // prior chunk's LDS reads done

        // ---- stage weighted-adj tile: 8 contiguous 1 KB row-segments per wave ----
        #pragma unroll
        for (int r = 0; r < 8; ++r) {
            const int row = (w << 3) + r;        // 0..31
            const size_t g = ((growbase + row) << 10) + (c << 8) + (lane << 2);
            float4 av = *(const float4*)(adj + g);
            int4   ev = *(const int4*)  (ea  + g);
            #define WSEL(e) __builtin_fmaf(__builtin_fmaf(__builtin_fmaf(c3, (float)(e), c2), (float)(e), c1), (float)(e), c0)
            float p0 = av.x * WSEL(ev.x);
            float p1 = av.y * WSEL(ev.y);
            float p2 = av.z * WSEL(ev.z);
            float p3 = av.w * WSEL(ev.w);
            #undef WSEL
            uint2 pk;
            pk.x = __builtin_amdgcn_perm(__float_as_uint(p1), __float_as_uint(p0), 0x07060302u);
            pk.y = __builtin_amdgcn_perm(__float_as_uint(p3), __float_as_uint(p2), 0x07060302u);
            *(uint2*)(lds + row * AW_STR + (lane << 3)) = pk;
        }
        // ---- stage xw chunk: 32 KB contiguous DMA (8 x 1 KB per wave) ----
        #pragma unroll
        for (int r = 0; r < 8; ++r) {
            const int i = (w << 3) + r;          // 0..31 tiles
            const int off = (i << 10) + (lane << 4);
            load_lds16(xwb + (c << 15) + off, lds + XW_OFF_L + off);
        }
        __syncthreads();                          // DMA drained + aw visible

        // ---- compute: 4 k-steps (kb = kh*4+s), 4 n-frags each ----
        #pragma unroll
        for (int s = 0; s < 4; ++s) {
            const int kb = (kh << 2) + s;         // 0..7 local 32-wide k-block
            short8 afr = *(const short8*)(lds + ((mf << 4) + m) * AW_STR + (kb << 6) + (q << 4));
            const char* xb = lds + XW_OFF_L + (kb << 12) + (lane << 4);
            short8 bf0 = *(const short8*)(xb);
            short8 bf1 = *(const short8*)(xb + 1024);
            short8 bf2 = *(const short8*)(xb + 2048);
            short8 bf3 = *(const short8*)(xb + 3072);
            acc0 = __builtin_amdgcn_mfma_f32_16x16x32_bf16(afr, bf0, acc0, 0, 0, 0);
            acc1 = __builtin_amdgcn_mfma_f32_16x16x32_bf16(afr, bf1, acc1, 0, 0, 0);
            acc2 = __builtin_amdgcn_mfma_f32_16x16x32_bf16(afr, bf2, acc2, 0, 0, 0);
            acc3 = __builtin_amdgcn_mfma_f32_16x16x32_bf16(afr, bf3, acc3, 0, 0, 0);
        }
    }

    // ---- 2-way kh combine via LDS (stride 68, conflict-free), plain RMW ----
    __syncthreads();                              // all LDS reads done -> reuse as scratch
    float* scratch = (float*)lds;                 // 2 x 1088 floats = 8.7 KB
    if (kh == 1) {
        float* buf = scratch + mf * 1088;
        #pragma unroll
        for (int rg = 0; rg < 4; ++rg) {
            int rbase = (q * 4 + rg) * 68 + m;
            buf[rbase]      = acc0[rg];
            buf[rbase + 16] = acc1[rg];
            buf[rbase + 32] = acc2[rg];
            buf[rbase + 48] = acc3[rg];
        }
    }
    __syncthreads();
    if (kh == 0) {
        const float* buf = scratch + mf * 1088;
        float* obase = out + (growbase + (mf << 4)) * 64;
        #pragma unroll
        for (int rg = 0; rg < 4; ++rg) {
            int rpad = (q * 4 + rg) * 68 + m;
            int rout = (q * 4 + rg) * 64 + m;
            #pragma unroll
            for (int n0 = 0; n0 < 4; ++n0) {
                float v = (n0 == 0 ? acc0[rg] : n0 == 1 ? acc1[rg] : n0 == 2 ? acc2[rg] : acc3[rg]);
                v += buf[rpad + n0 * 16];
                obase[rout + n0 * 16] += v;       // block owns these rows: no atomics
            }
        }
    }
}

extern "C" void kernel_launch(void* const* d_in, const int* in_sizes, int n_in,
                              void* d_out, int out_size, void* d_ws, size_t ws_size,
                              hipStream_t stream) {
    const float* x      = (const float*)d_in[0];
    const float* adj    = (const float*)d_in[1];
    const int*   ea     = (const int*)  d_in[2];
    const float* W_rel  = (const float*)d_in[3];
    const float* b_rel  = (const float*)d_in[4];
    const float* W_root = (const float*)d_in[5];
    const float* w_edge = (const float*)d_in[6];
    float* out = (float*)d_out;

    unsigned short* xw_sw = (unsigned short*)d_ws;   // B*N*C bf16 = 2 MiB

    precompute<<<BB * NN / 16, 256, 0, stream>>>(x, W_rel, W_root, b_rel, xw_sw, out);
    gnn_mfma<<<BB * (NN / 32), 256, 0, stream>>>(adj, ea, w_edge, xw_sw, out);
}